// Round 20
// baseline (4349.261 us; speedup 1.0000x reference)
//
#include <hip/hip_runtime.h>

#define NBATCH 256
#define SLEN   2048
#define NTAG   64
#define BOS_T  1
#define EOS_T  2

#define BT_BYTES  131072
#define RING_ROWS 32
#define RING_BYTES (RING_ROWS * NTAG * 4)          // 8192
#define FLAG_OFF  (BT_BYTES + RING_BYTES)          // 139264
#define PRG_OFF   (FLAG_OFF + 16)                  // 139280
#define MAPS_OFF  (PRG_OFF + 16)                   // 139296 (64x64 u8)
#define BTAG_OFF  (MAPS_OFF + 4096)                // 143392 (65 x i32)
#define LDS_BYTES (BTAG_OFF + 272)                 // 143664 < 160K

#define GRING_FLOATS (RING_ROWS * NTAG)            // per batch
#define GRING_BYTES  ((size_t)NBATCH * GRING_FLOATS * 4)   // 2 MB

typedef float f32x2 __attribute__((ext_vector_type(2)));
typedef float f32x4 __attribute__((ext_vector_type(4)));

#define Q16(X) X(0) X(1) X(2) X(3) X(4) X(5) X(6) X(7) \
               X(8) X(9) X(10) X(11) X(12) X(13) X(14) X(15)

// T column as 32 f32x2 pairs
#define DECL_TP(q) \
  f32x2 tpA##q = { trans[(4*(q)+0)*NTAG + lane], trans[(4*(q)+1)*NTAG + lane] }; \
  f32x2 tpB##q = { trans[(4*(q)+2)*NTAG + lane], trans[(4*(q)+3)*NTAG + lane] };
#define KEEP_TP(q) asm volatile("" : "+v"(tpA##q), "+v"(tpB##q));

// producer: loop-carried row registers (read back right after the write)
#define DECL_RRV(q) f32x4 rr##q;
#define LOAD_RR(q)  rr##q = rp[q];

// producer packed candidates: v_pk_add_f32 + quad max (exact)
#define PKC(q) \
  f32x2 cpA##q = (f32x2){rr##q[0], rr##q[1]} + tpA##q; \
  f32x2 cpB##q = (f32x2){rr##q[2], rr##q[3]} + tpB##q; \
  float qm##q = fmaxf(fmaxf(fmaxf(cpA##q[0], cpA##q[1]), cpB##q[0]), cpB##q[1]);

#define FM3(x, y, z) fmaxf(fmaxf((x), (y)), (z))

// consumer row registers: from LDS ring, or volatile (sc0, L1-bypass) global
#define DECL_CRV(q) f32x4 cr##q;
#define LOADL(q)    cr##q = rp[q];
#define LOADG(q)    { const volatile float* _g = gr + (q)*4; \
                      cr##q[0]=_g[0]; cr##q[1]=_g[1]; cr##q[2]=_g[2]; cr##q[3]=_g[3]; }

#define MKCD(q, a0, a1, a2, a3) \
  float cd##a0 = cr##q[0] + tpA##q[0]; float cd##a1 = cr##q[1] + tpA##q[1]; \
  float cd##a2 = cr##q[2] + tpB##q[0]; float cd##a3 = cr##q[3] + tpB##q[1];
#define ALL_CD() \
  MKCD(0,0,1,2,3)      MKCD(1,4,5,6,7)      MKCD(2,8,9,10,11)    MKCD(3,12,13,14,15) \
  MKCD(4,16,17,18,19)  MKCD(5,20,21,22,23)  MKCD(6,24,25,26,27)  MKCD(7,28,29,30,31) \
  MKCD(8,32,33,34,35)  MKCD(9,36,37,38,39)  MKCD(10,40,41,42,43) MKCD(11,44,45,46,47) \
  MKCD(12,48,49,50,51) MKCD(13,52,53,54,55) MKCD(14,56,57,58,59) MKCD(15,60,61,62,63)

// exact first-occurrence argmax tournament (ascending pairs, >= left-bias)
#define LEAF(i, pa, pb) \
  float va##i; int ia##i; { bool g_ = (cd##pa >= cd##pb); \
    va##i = g_ ? cd##pa : cd##pb; ia##i = g_ ? (pa) : (pb); }
#define MRG(vo, io, vA, iA, vB, iB) \
  float vo; int io; { bool g_ = ((vA) >= (vB)); \
    vo = g_ ? (vA) : (vB); io = g_ ? (iA) : (iB); }

__global__ __launch_bounds__(256)
__attribute__((amdgpu_waves_per_eu(1, 1)))
void crf_viterbi(const float* __restrict__ emissions,  // [B,S,C]
                 const float* __restrict__ mask,       // [B,S]
                 const float* __restrict__ trans,      // [C,C]
                 int* __restrict__ out,                // [B,S] int32 tags
                 float* __restrict__ gring)            // [B][32][64] or null
{
    extern __shared__ unsigned char lds[];
    unsigned char* bt   = lds;                               // [S-1][64]
    float*         ring = (float*)(lds + BT_BYTES);          // [32][64]
    volatile unsigned* flg = (volatile unsigned*)(lds + FLAG_OFF);
    volatile unsigned* prg = (volatile unsigned*)(lds + PRG_OFF);
    unsigned char* maps = lds + MAPS_OFF;                    // [64][64]
    int*           btag = (int*)(lds + BTAG_OFF);            // [65]

    const int b    = blockIdx.x;
    const int tid  = threadIdx.x;
    const int w    = tid >> 6;                               // wave 0..3
    const int lane = tid & 63;
    const bool useg = (gring != nullptr);                    // uniform
    float* gbase = useg ? (gring + (size_t)b * GRING_FLOATS) : nullptr;

    if (tid == 0) flg[0] = 0u;
    if (tid >= 1 && tid <= 3) prg[tid] = 0u;
    __syncthreads();

    // length = sum(mask[b,:])
    const float* mrow = mask + (size_t)b * SLEN;
    float msum = 0.f;
    #pragma unroll
    for (int k = 0; k < SLEN / 64; ++k) msum += mrow[lane + k * 64];
    #pragma unroll
    for (int off = 32; off >= 1; off >>= 1) msum += __shfl_xor(msum, off, 64);
    const int len = (int)msum;                               // in [1024, 2048]
    const int K   = (len - 1 + 31) >> 5;                     // backtrace chunks

    const float* E = emissions + (size_t)b * SLEN * NTAG;
    int* orow = out + (size_t)b * SLEN;

    if (w == 0) {
        // ---- producer: value-only; LDS readback for self; global ring copy
        // feeds consumers (keeps their 16xB128 bursts OFF the LDS pipe) ----
        Q16(DECL_TP)
        Q16(DECL_RRV)

        float a = E[lane] + tpA0[1];                         // alpha0 (+T[BOS])
        ring[lane] = a;                                      // row 0 -> slot 0
        if (useg) gbase[lane] = a;                           // global row 0
        {
            const f32x4* rp = (const f32x4*)ring;
            Q16(LOAD_RR)                                     // read back row 0
        }
        asm volatile("" ::: "memory");
        if (lane == 0) flg[0] = 1u;

        float e0 = E[NTAG + lane];
        float e1 = E[((2 < len) ? 2 : (len - 1)) * NTAG + lane];
        float e2 = E[((3 < len) ? 3 : (len - 1)) * NTAG + lane];
        float e3 = E[((4 < len) ? 4 : (len - 1)) * NTAG + lane];

        for (int t = 1; t < len; ++t) {
            float emit = e0; e0 = e1; e1 = e2; e2 = e3;
            int tn = (t + 4 < len) ? (t + 4) : (len - 1);
            e3 = E[tn * NTAG + lane];

            // compute from rr (= row t-1, already in registers)
            Q16(PKC)
            float s0 = FM3(qm0,  qm1,  qm2);
            float s1 = FM3(qm3,  qm4,  qm5);
            float s2 = FM3(qm6,  qm7,  qm8);
            float s3 = FM3(qm9,  qm10, qm11);
            float s4 = FM3(qm12, qm13, qm14);
            float u0 = FM3(s0, s1, s2);
            float u1 = fmaxf(s3, s4);
            float mx = FM3(u0, u1, qm15);

            a = mx + emit;
            const int slot = t & (RING_ROWS - 1);
            ring[(slot << 6) + lane] = a;                    // LDS row t
            {
                const f32x4* rp = (const f32x4*)(ring + (slot << 6));
                Q16(LOAD_RR)                                 // read back row t
            }
            if (useg) {
                gbase[(slot << 6) + lane] = a;               // global row t
                // <=14 outstanding vmem ops (2/iter) => stores from >=7 iters
                // ago retired; certifies rows <= t-7 visible when flag = t+1
                asm volatile("s_waitcnt vmcnt(14)" ::: "memory");
            }
            asm volatile("" ::: "memory");
            if (lane == 0) flg[0] = (unsigned)(t + 1);

            // ring-overwrite guard (32-row ring, threshold t-16)
            if ((t & 7) == 0) {
                int g = 0;
                for (;;) {
                    unsigned m1_ = prg[1], m2_ = prg[2], m3_ = prg[3];
                    unsigned mn = m1_ < m2_ ? m1_ : m2_;
                    mn = mn < m3_ ? mn : m3_;
                    if ((int)mn >= t - 16 || ++g > 2000000) break;
                    __builtin_amdgcn_s_sleep(8);
                }
            }
            Q16(KEEP_TP)                                     // pin T column
        }

        // unblock tail consumers: all global stores complete, then sentinel
        if (useg) asm volatile("s_waitcnt vmcnt(0)" ::: "memory");
        asm volatile("" ::: "memory");
        if (lane == 0) flg[0] = (unsigned)(len + 64);

        // final scores + argmax (value desc, index asc)
        float fin = a + trans[lane * NTAG + EOS_T];
        float v = fin; int idx = lane;
        #pragma unroll
        for (int off = 1; off < 64; off <<= 1) {
            float ov = __shfl_xor(v, off, 64);
            int   oi = __shfl_xor(idx, off, 64);
            if (ov > v || (ov == v && oi < idx)) { v = ov; idx = oi; }
        }
        int best_last = idx;

        for (int i = len + lane; i < SLEN; i += 64) orow[i] = 0;   // PAD
        if (lane == 0) {
            orow[len - 1] = best_last;
            btag[K] = best_last;                             // backtrace seed
        }
    } else {
        // ---- consumers: lagged exact argmax -> bt; rows from L2 (volatile)
        // when gring present, else LDS (r19 path) ----
        Q16(DECL_TP)
        for (int t = w; t < len; t += 3) {
            const unsigned need = useg ? (unsigned)(t + 7) : (unsigned)t;
            int g = 0;
            while (flg[0] < need) {
                __builtin_amdgcn_s_sleep(16);
                if (++g > 200000) break;
            }
            asm volatile("" ::: "memory");

            const int slot = (t - 1) & (RING_ROWS - 1);
            Q16(DECL_CRV)
            if (useg) {
                const volatile float* gr = gbase + (slot << 6);
                Q16(LOADG)
            } else {
                const f32x4* rp = (const f32x4*)(ring + (slot << 6));
                Q16(LOADL)
            }
            ALL_CD()

            LEAF(0,  0,  1)  LEAF(1,  2,  3)  LEAF(2,  4,  5)  LEAF(3,  6,  7)
            LEAF(4,  8,  9)  LEAF(5,  10, 11) LEAF(6,  12, 13) LEAF(7,  14, 15)
            LEAF(8,  16, 17) LEAF(9,  18, 19) LEAF(10, 20, 21) LEAF(11, 22, 23)
            LEAF(12, 24, 25) LEAF(13, 26, 27) LEAF(14, 28, 29) LEAF(15, 30, 31)
            LEAF(16, 32, 33) LEAF(17, 34, 35) LEAF(18, 36, 37) LEAF(19, 38, 39)
            LEAF(20, 40, 41) LEAF(21, 42, 43) LEAF(22, 44, 45) LEAF(23, 46, 47)
            LEAF(24, 48, 49) LEAF(25, 50, 51) LEAF(26, 52, 53) LEAF(27, 54, 55)
            LEAF(28, 56, 57) LEAF(29, 58, 59) LEAF(30, 60, 61) LEAF(31, 62, 63)
            MRG(vb0,  ib0,  va0,  ia0,  va1,  ia1)   MRG(vb1,  ib1,  va2,  ia2,  va3,  ia3)
            MRG(vb2,  ib2,  va4,  ia4,  va5,  ia5)   MRG(vb3,  ib3,  va6,  ia6,  va7,  ia7)
            MRG(vb4,  ib4,  va8,  ia8,  va9,  ia9)   MRG(vb5,  ib5,  va10, ia10, va11, ia11)
            MRG(vb6,  ib6,  va12, ia12, va13, ia13)  MRG(vb7,  ib7,  va14, ia14, va15, ia15)
            MRG(vb8,  ib8,  va16, ia16, va17, ia17)  MRG(vb9,  ib9,  va18, ia18, va19, ia19)
            MRG(vb10, ib10, va20, ia20, va21, ia21)  MRG(vb11, ib11, va22, ia22, va23, ia23)
            MRG(vb12, ib12, va24, ia24, va25, ia25)  MRG(vb13, ib13, va26, ia26, va27, ia27)
            MRG(vb14, ib14, va28, ia28, va29, ia29)  MRG(vb15, ib15, va30, ia30, va31, ia31)
            MRG(vc0, ic0, vb0,  ib0,  vb1,  ib1)     MRG(vc1, ic1, vb2,  ib2,  vb3,  ib3)
            MRG(vc2, ic2, vb4,  ib4,  vb5,  ib5)     MRG(vc3, ic3, vb6,  ib6,  vb7,  ib7)
            MRG(vc4, ic4, vb8,  ib8,  vb9,  ib9)     MRG(vc5, ic5, vb10, ib10, vb11, ib11)
            MRG(vc6, ic6, vb12, ib12, vb13, ib13)    MRG(vc7, ic7, vb14, ib14, vb15, ib15)
            MRG(vd0, id0, vc0, ic0, vc1, ic1)        MRG(vd1, id1, vc2, ic2, vc3, ic3)
            MRG(vd2, id2, vc4, ic4, vc5, ic5)        MRG(vd3, id3, vc6, ic6, vc7, ic7)
            MRG(ve0, ie0, vd0, id0, vd1, id1)        MRG(ve1, ie1, vd2, id2, vd3, id3)
            MRG(vf0, if0, ve0, ie0, ve1, ie1)

            bt[(t - 1) * NTAG + lane] = (unsigned char)if0;
            asm volatile("" ::: "memory");
            prg[w] = (unsigned)t;
            Q16(KEEP_TP)
        }
        asm volatile("" ::: "memory");
        prg[w] = 0x7fffffffu;                                // done marker
    }

    // ==================== join: bt + seed visible to all ====================
    __syncthreads();

    // ---- phase 1: per-chunk tag maps; wave w owns chunks w, w+4, ... ----
    {
        #define C16(X) X(0) X(1) X(2) X(3) X(4) X(5) X(6) X(7) \
                       X(8) X(9) X(10) X(11) X(12) X(13) X(14) X(15)
        #define DECLCUR(i) \
          const int k##i = w + 4*(i); const int base##i = k##i << 5; \
          int top##i = base##i + 32; if (top##i > len - 1) top##i = len - 1; \
          const int steps##i = (k##i < K) ? (top##i - base##i) : 0; \
          int cur##i = lane;
        C16(DECLCUR)
        for (int j = 0; j < 32; ++j) {
            #define STEPC(i) if (j < steps##i) \
                cur##i = bt[(top##i - 1 - j) * NTAG + cur##i];
            C16(STEPC)
        }
        #define STOREM(i) if (k##i < K) maps[(k##i << 6) + lane] = (unsigned char)cur##i;
        C16(STOREM)
    }
    __syncthreads();

    // ---- phase 2: compose boundary tags (wave 0) ----
    if (w == 0) {
        int cur = btag[K];
        for (int k = K - 1; k >= 0; --k) {
            cur = maps[(k << 6) + cur];
            if (lane == 0) btag[k] = cur;
        }
    }
    __syncthreads();

    // ---- phase 3: guided re-chase, write outputs ----
    {
        #define DECLR(i) \
          const int rk##i = w + 4*(i); const int rb##i = rk##i << 5; \
          int rt##i = rb##i + 32; if (rt##i > len - 1) rt##i = len - 1; \
          const int rs##i = (rk##i < K) ? (rt##i - rb##i) : 0; \
          int rc##i = (rk##i < K) ? btag[rk##i + 1] : 0;
        C16(DECLR)
        for (int j = 0; j < 32; ++j) {
            #define STEPR(i) if (j < rs##i) { \
                const int t_ = rt##i - 1 - j; \
                rc##i = bt[t_ * NTAG + rc##i]; \
                if (lane == 0) orow[t_] = rc##i; }
            C16(STEPR)
        }
    }
}

extern "C" void kernel_launch(void* const* d_in, const int* in_sizes, int n_in,
                              void* d_out, int out_size, void* d_ws, size_t ws_size,
                              hipStream_t stream) {
    const float* emissions = (const float*)d_in[0];
    const float* mask      = (const float*)d_in[1];
    const float* trans     = (const float*)d_in[2];
    int* out = (int*)d_out;

    // use the global ring only if the workspace is big enough (2 MB)
    float* gring = (ws_size >= GRING_BYTES) ? (float*)d_ws : nullptr;

    (void)hipFuncSetAttribute((const void*)crf_viterbi,
                              hipFuncAttributeMaxDynamicSharedMemorySize,
                              LDS_BYTES);

    crf_viterbi<<<NBATCH, 256, LDS_BYTES, stream>>>(emissions, mask, trans, out, gring);
}

// Round 22
// 1136.727 us; speedup vs baseline: 3.8261x; 3.8261x over previous
//
#include <hip/hip_runtime.h>

#define NBATCH 256
#define SLEN   2048
#define NTAG   64
#define BOS_T  1
#define EOS_T  2

#define BT_BYTES  131072
#define RING_ROWS 32
#define RING_BYTES (RING_ROWS * NTAG * 4)          // 8192
#define FLAG_OFF  (BT_BYTES + RING_BYTES)          // 139264
#define PRG_OFF   (FLAG_OFF + 16)                  // 139280
#define MAPS_OFF  (PRG_OFF + 16)                   // 139296 (64x64 u8)
#define BTAG_OFF  (MAPS_OFF + 4096)                // 143392 (65 x i32)
#define LDS_BYTES (BTAG_OFF + 272)                 // 143664 < 160K

typedef float f32x2 __attribute__((ext_vector_type(2)));
typedef float f32x4 __attribute__((ext_vector_type(4)));
typedef unsigned uint2v __attribute__((ext_vector_type(2)));

#define Q16(X) X(0) X(1) X(2) X(3) X(4) X(5) X(6) X(7) \
               X(8) X(9) X(10) X(11) X(12) X(13) X(14) X(15)

// ---------------- producer: register all-gather (builtin swaps) ----------
// hedged permlane swaps: direction probed at runtime with the SAME builtin.
// NOTE: ext_vector component access via [0]/[1] (this clang rejects .x/.y here)
#define SWAP32(x, lo, hi) float lo, hi; { \
    uint2v _r = __builtin_amdgcn_permlane32_swap(__float_as_uint(x), __float_as_uint(x), false, false); \
    float _a = __uint_as_float(_r[0]), _b = __uint_as_float(_r[1]); \
    lo = lo32x ? _a : _b; hi = lo32x ? _b : _a; }
#define SWAP16(x, lo, hi) float lo, hi; { \
    uint2v _r = __builtin_amdgcn_permlane16_swap(__float_as_uint(x), __float_as_uint(x), false, false); \
    float _a = __uint_as_float(_r[0]), _b = __uint_as_float(_r[1]); \
    lo = lo16x ? _a : _b; hi = lo16x ? _b : _a; }

// DPP quad_perm (validated r13+r18): 0x4E = l^2, 0xB1 = l^1
#define DPPF(dst, src, ctrl) \
  float dst = __int_as_float(__builtin_amdgcn_update_dpp(0, __float_as_int(src), ctrl, 0xF, 0xF, true));
#define D2(e, o) DPPF(o, e, 0x4E)
#define D1(e, o) DPPF(o, e, 0xB1)

#define N64(X) \
  X(0)  X(1)  X(2)  X(3)  X(4)  X(5)  X(6)  X(7)  \
  X(8)  X(9)  X(10) X(11) X(12) X(13) X(14) X(15) \
  X(16) X(17) X(18) X(19) X(20) X(21) X(22) X(23) \
  X(24) X(25) X(26) X(27) X(28) X(29) X(30) X(31) \
  X(32) X(33) X(34) X(35) X(36) X(37) X(38) X(39) \
  X(40) X(41) X(42) X(43) X(44) X(45) X(46) X(47) \
  X(48) X(49) X(50) X(51) X(52) X(53) X(54) X(55) \
  X(56) X(57) X(58) X(59) X(60) X(61) X(62) X(63)

// v_n = a[(n&0x30) | ((lane^n)&0xF)] -> T preloaded in the same order
#define DECL_TG(n) \
  float tg##n = trans[((((n) & 0x30) | ((lane ^ (n)) & 0x0F)) * NTAG) + lane];
#define KEEP_TG(n) asm volatile("" : "+v"(tg##n));
#define CDX(n) float cd##n = v##n + tg##n;

#define FM3(x, y, z) fmaxf(fmaxf((x), (y)), (z))

// ---------------- consumer (verbatim r15/r19, passing) ----------------
#define DECL_TP(q) \
  f32x2 tpA##q = { trans[(4*(q)+0)*NTAG + lane], trans[(4*(q)+1)*NTAG + lane] }; \
  f32x2 tpB##q = { trans[(4*(q)+2)*NTAG + lane], trans[(4*(q)+3)*NTAG + lane] };
#define KEEP_TP(q) asm volatile("" : "+v"(tpA##q), "+v"(tpB##q));
#define DECL_RR(q) f32x4 cr##q = rp[q];
#define MKCD(q, a0, a1, a2, a3) \
  float cd##a0 = cr##q[0] + tpA##q[0]; float cd##a1 = cr##q[1] + tpA##q[1]; \
  float cd##a2 = cr##q[2] + tpB##q[0]; float cd##a3 = cr##q[3] + tpB##q[1];
#define ALL_CD() \
  MKCD(0,0,1,2,3)      MKCD(1,4,5,6,7)      MKCD(2,8,9,10,11)    MKCD(3,12,13,14,15) \
  MKCD(4,16,17,18,19)  MKCD(5,20,21,22,23)  MKCD(6,24,25,26,27)  MKCD(7,28,29,30,31) \
  MKCD(8,32,33,34,35)  MKCD(9,36,37,38,39)  MKCD(10,40,41,42,43) MKCD(11,44,45,46,47) \
  MKCD(12,48,49,50,51) MKCD(13,52,53,54,55) MKCD(14,56,57,58,59) MKCD(15,60,61,62,63)
#define LEAF(i, pa, pb) \
  float va##i; int ia##i; { bool g_ = (cd##pa >= cd##pb); \
    va##i = g_ ? cd##pa : cd##pb; ia##i = g_ ? (pa) : (pb); }
#define MRG(vo, io, vA, iA, vB, iB) \
  float vo; int io; { bool g_ = ((vA) >= (vB)); \
    vo = g_ ? (vA) : (vB); io = g_ ? (iA) : (iB); }

__global__ __launch_bounds__(256)
__attribute__((amdgpu_waves_per_eu(1, 1)))
void crf_viterbi(const float* __restrict__ emissions,  // [B,S,C]
                 const float* __restrict__ mask,       // [B,S]
                 const float* __restrict__ trans,      // [C,C]
                 int* __restrict__ out)                // [B,S] int32 tags
{
    extern __shared__ unsigned char lds[];
    unsigned char* bt   = lds;                               // [S-1][64]
    float*         ring = (float*)(lds + BT_BYTES);          // [32][64]
    volatile unsigned* flg = (volatile unsigned*)(lds + FLAG_OFF);
    volatile unsigned* prg = (volatile unsigned*)(lds + PRG_OFF);
    unsigned char* maps = lds + MAPS_OFF;                    // [64][64]
    int*           btag = (int*)(lds + BTAG_OFF);            // [65]

    const int b    = blockIdx.x;
    const int tid  = threadIdx.x;
    const int w    = tid >> 6;                               // wave 0..3
    const int lane = tid & 63;

    if (tid == 0) flg[0] = 0u;
    if (tid >= 1 && tid <= 3) prg[tid] = 0u;
    __syncthreads();

    // length = sum(mask[b,:])
    const float* mrow = mask + (size_t)b * SLEN;
    float msum = 0.f;
    #pragma unroll
    for (int k = 0; k < SLEN / 64; ++k) msum += mrow[lane + k * 64];
    #pragma unroll
    for (int off = 32; off >= 1; off >>= 1) msum += __shfl_xor(msum, off, 64);
    const int len = (int)msum;                               // in [1024, 2048]
    const int K   = (len - 1 + 31) >> 5;                     // backtrace chunks

    const float* E = emissions + (size_t)b * SLEN * NTAG;
    int* orow = out + (size_t)b * SLEN;

    if (w == 0) {
        // ---- direction probes with the BUILTIN (tests the real mechanism) ----
        uint2v p32 = __builtin_amdgcn_permlane32_swap((unsigned)lane, (unsigned)lane, false, false);
        const bool lo32x = ((p32[0] & 32u) == 0u);           // wave-uniform
        uint2v p16 = __builtin_amdgcn_permlane16_swap((unsigned)lane, (unsigned)lane, false, false);
        const bool lo16x = ((p16[0] & 16u) == 0u);           // wave-uniform

        N64(DECL_TG)                                         // permuted T column

        float a = E[lane] + trans[BOS_T * NTAG + lane];      // alpha0
        ring[lane] = a;
        asm volatile("" ::: "memory");
        if (lane == 0) flg[0] = 1u;

        float e0 = E[NTAG + lane];
        float e1 = E[((2 < len) ? 2 : (len - 1)) * NTAG + lane];
        float e2 = E[((3 < len) ? 3 : (len - 1)) * NTAG + lane];
        float e3 = E[((4 < len) ? 4 : (len - 1)) * NTAG + lane];

        for (int t = 1; t < len; ++t) {
            float emit = e0; e0 = e1; e1 = e2; e2 = e3;
            int tn = (t + 4 < len) ? (t + 4) : (len - 1);
            e3 = E[tn * NTAG + lane];

            // ---- all-gather: v_n = a[(n&0x30)|((lane^n)&0xF)] ----
            SWAP32(a,  A0, A1)                               // bit5 absolute
            SWAP16(A0, v0,  v16)                             // bit4 absolute
            SWAP16(A1, v32, v48)
            // bits 3,2: ONE dependent level of bpermutes (masks 8,4,12)
            float v8  = __shfl_xor(v0,  8, 64);
            float v4  = __shfl_xor(v0,  4, 64);
            float v12 = __shfl_xor(v0, 12, 64);
            float v24 = __shfl_xor(v16, 8, 64);
            float v20 = __shfl_xor(v16, 4, 64);
            float v28 = __shfl_xor(v16,12, 64);
            float v40 = __shfl_xor(v32, 8, 64);
            float v36 = __shfl_xor(v32, 4, 64);
            float v44 = __shfl_xor(v32,12, 64);
            float v56 = __shfl_xor(v48, 8, 64);
            float v52 = __shfl_xor(v48, 4, 64);
            float v60 = __shfl_xor(v48,12, 64);
            // bits 1,0: quad_perm DPP
            D2(v0, v2)   D2(v4, v6)   D2(v8, v10)  D2(v12, v14)
            D2(v16, v18) D2(v20, v22) D2(v24, v26) D2(v28, v30)
            D2(v32, v34) D2(v36, v38) D2(v40, v42) D2(v44, v46)
            D2(v48, v50) D2(v52, v54) D2(v56, v58) D2(v60, v62)
            D1(v0, v1)   D1(v2, v3)   D1(v4, v5)   D1(v6, v7)
            D1(v8, v9)   D1(v10, v11) D1(v12, v13) D1(v14, v15)
            D1(v16, v17) D1(v18, v19) D1(v20, v21) D1(v22, v23)
            D1(v24, v25) D1(v26, v27) D1(v28, v29) D1(v30, v31)
            D1(v32, v33) D1(v34, v35) D1(v36, v37) D1(v38, v39)
            D1(v40, v41) D1(v42, v43) D1(v44, v45) D1(v46, v47)
            D1(v48, v49) D1(v50, v51) D1(v52, v53) D1(v54, v55)
            D1(v56, v57) D1(v58, v59) D1(v60, v61) D1(v62, v63)

            N64(CDX)                                         // cd_n = v_n + tg_n

            // 64 -> 1 max via max3 tree (exact: max associative)
            float l0  = FM3(cd0,  cd1,  cd2);
            float l1  = FM3(cd3,  cd4,  cd5);
            float l2  = FM3(cd6,  cd7,  cd8);
            float l3  = FM3(cd9,  cd10, cd11);
            float l4  = FM3(cd12, cd13, cd14);
            float l5  = FM3(cd15, cd16, cd17);
            float l6  = FM3(cd18, cd19, cd20);
            float l7  = FM3(cd21, cd22, cd23);
            float l8  = FM3(cd24, cd25, cd26);
            float l9  = FM3(cd27, cd28, cd29);
            float l10 = FM3(cd30, cd31, cd32);
            float l11 = FM3(cd33, cd34, cd35);
            float l12 = FM3(cd36, cd37, cd38);
            float l13 = FM3(cd39, cd40, cd41);
            float l14 = FM3(cd42, cd43, cd44);
            float l15 = FM3(cd45, cd46, cd47);
            float l16 = FM3(cd48, cd49, cd50);
            float l17 = FM3(cd51, cd52, cd53);
            float l18 = FM3(cd54, cd55, cd56);
            float l19 = FM3(cd57, cd58, cd59);
            float l20 = FM3(cd60, cd61, cd62);
            float m0 = FM3(l0,  l1,  l2);
            float m1 = FM3(l3,  l4,  l5);
            float m2 = FM3(l6,  l7,  l8);
            float m3 = FM3(l9,  l10, l11);
            float m4 = FM3(l12, l13, l14);
            float m5 = FM3(l15, l16, l17);
            float m6 = FM3(l18, l19, l20);
            float n0 = FM3(m0, m1, m2);
            float n1 = FM3(m3, m4, m5);
            float mx = fmaxf(FM3(n0, n1, m6), cd63);

            a = mx + emit;
            ring[((t & (RING_ROWS - 1)) << 6) + lane] = a;   // publish row t
            asm volatile("" ::: "memory");
            if (lane == 0) flg[0] = (unsigned)(t + 1);

            // ring-overwrite guard (32-row ring, threshold t-16)
            if ((t & 7) == 0) {
                int g = 0;
                for (;;) {
                    unsigned m1_ = prg[1], m2_ = prg[2], m3_ = prg[3];
                    unsigned mn = m1_ < m2_ ? m1_ : m2_;
                    mn = mn < m3_ ? mn : m3_;
                    if ((int)mn >= t - 16 || ++g > 2000000) break;
                    __builtin_amdgcn_s_sleep(8);
                }
            }
            N64(KEEP_TG)                                     // pin T column
        }

        // final scores + argmax (value desc, index asc)
        float fin = a + trans[lane * NTAG + EOS_T];
        float v = fin; int idx = lane;
        #pragma unroll
        for (int off = 1; off < 64; off <<= 1) {
            float ov = __shfl_xor(v, off, 64);
            int   oi = __shfl_xor(idx, off, 64);
            if (ov > v || (ov == v && oi < idx)) { v = ov; idx = oi; }
        }
        int best_last = idx;

        for (int i = len + lane; i < SLEN; i += 64) orow[i] = 0;   // PAD
        if (lane == 0) {
            orow[len - 1] = best_last;
            btag[K] = best_last;                             // backtrace seed
        }
    } else {
        // ---- consumers: lagged exact argmax -> bt (verbatim r15/r19) ----
        Q16(DECL_TP)
        for (int t = w; t < len; t += 3) {
            int g = 0;
            while (flg[0] < (unsigned)t) {                   // rows <= t-1 ready
                __builtin_amdgcn_s_sleep(16);
                if (++g > 200000) break;
            }
            asm volatile("" ::: "memory");

            const f32x4* rp = (const f32x4*)(ring + (((t - 1) & (RING_ROWS - 1)) << 6));
            Q16(DECL_RR)
            ALL_CD()

            LEAF(0,  0,  1)  LEAF(1,  2,  3)  LEAF(2,  4,  5)  LEAF(3,  6,  7)
            LEAF(4,  8,  9)  LEAF(5,  10, 11) LEAF(6,  12, 13) LEAF(7,  14, 15)
            LEAF(8,  16, 17) LEAF(9,  18, 19) LEAF(10, 20, 21) LEAF(11, 22, 23)
            LEAF(12, 24, 25) LEAF(13, 26, 27) LEAF(14, 28, 29) LEAF(15, 30, 31)
            LEAF(16, 32, 33) LEAF(17, 34, 35) LEAF(18, 36, 37) LEAF(19, 38, 39)
            LEAF(20, 40, 41) LEAF(21, 42, 43) LEAF(22, 44, 45) LEAF(23, 46, 47)
            LEAF(24, 48, 49) LEAF(25, 50, 51) LEAF(26, 52, 53) LEAF(27, 54, 55)
            LEAF(28, 56, 57) LEAF(29, 58, 59) LEAF(30, 60, 61) LEAF(31, 62, 63)
            MRG(vb0,  ib0,  va0,  ia0,  va1,  ia1)   MRG(vb1,  ib1,  va2,  ia2,  va3,  ia3)
            MRG(vb2,  ib2,  va4,  ia4,  va5,  ia5)   MRG(vb3,  ib3,  va6,  ia6,  va7,  ia7)
            MRG(vb4,  ib4,  va8,  ia8,  va9,  ia9)   MRG(vb5,  ib5,  va10, ia10, va11, ia11)
            MRG(vb6,  ib6,  va12, ia12, va13, ia13)  MRG(vb7,  ib7,  va14, ia14, va15, ia15)
            MRG(vb8,  ib8,  va16, ia16, va17, ia17)  MRG(vb9,  ib9,  va18, ia18, va19, ia19)
            MRG(vb10, ib10, va20, ia20, va21, ia21)  MRG(vb11, ib11, va22, ia22, va23, ia23)
            MRG(vb12, ib12, va24, ia24, va25, ia25)  MRG(vb13, ib13, va26, ia26, va27, ia27)
            MRG(vb14, ib14, va28, ia28, va29, ia29)  MRG(vb15, ib15, va30, ia30, va31, ia31)
            MRG(vc0, ic0, vb0,  ib0,  vb1,  ib1)     MRG(vc1, ic1, vb2,  ib2,  vb3,  ib3)
            MRG(vc2, ic2, vb4,  ib4,  vb5,  ib5)     MRG(vc3, ic3, vb6,  ib6,  vb7,  ib7)
            MRG(vc4, ic4, vb8,  ib8,  vb9,  ib9)     MRG(vc5, ic5, vb10, ib10, vb11, ib11)
            MRG(vc6, ic6, vb12, ib12, vb13, ib13)    MRG(vc7, ic7, vb14, ib14, vb15, ib15)
            MRG(vd0, id0, vc0, ic0, vc1, ic1)        MRG(vd1, id1, vc2, ic2, vc3, ic3)
            MRG(vd2, id2, vc4, ic4, vc5, ic5)        MRG(vd3, id3, vc6, ic6, vc7, ic7)
            MRG(ve0, ie0, vd0, id0, vd1, id1)        MRG(ve1, ie1, vd2, id2, vd3, id3)
            MRG(vf0, if0, ve0, ie0, ve1, ie1)

            bt[(t - 1) * NTAG + lane] = (unsigned char)if0;
            asm volatile("" ::: "memory");
            prg[w] = (unsigned)t;
            Q16(KEEP_TP)
        }
    }

    // ==================== join: bt + seed visible to all ====================
    __syncthreads();

    // ---- phase 1: per-chunk tag maps; wave w owns chunks w, w+4, ... ----
    {
        #define C16(X) X(0) X(1) X(2) X(3) X(4) X(5) X(6) X(7) \
                       X(8) X(9) X(10) X(11) X(12) X(13) X(14) X(15)
        #define DECLCUR(i) \
          const int k##i = w + 4*(i); const int base##i = k##i << 5; \
          int top##i = base##i + 32; if (top##i > len - 1) top##i = len - 1; \
          const int steps##i = (k##i < K) ? (top##i - base##i) : 0; \
          int cur##i = lane;
        C16(DECLCUR)
        for (int j = 0; j < 32; ++j) {
            #define STEPC(i) if (j < steps##i) \
                cur##i = bt[(top##i - 1 - j) * NTAG + cur##i];
            C16(STEPC)
        }
        #define STOREM(i) if (k##i < K) maps[(k##i << 6) + lane] = (unsigned char)cur##i;
        C16(STOREM)
    }
    __syncthreads();

    // ---- phase 2: compose boundary tags (wave 0) ----
    if (w == 0) {
        int cur = btag[K];
        for (int k = K - 1; k >= 0; --k) {
            cur = maps[(k << 6) + cur];
            if (lane == 0) btag[k] = cur;
        }
    }
    __syncthreads();

    // ---- phase 3: guided re-chase, write outputs ----
    {
        #define DECLR(i) \
          const int rk##i = w + 4*(i); const int rb##i = rk##i << 5; \
          int rt##i = rb##i + 32; if (rt##i > len - 1) rt##i = len - 1; \
          const int rs##i = (rk##i < K) ? (rt##i - rb##i) : 0; \
          int rc##i = (rk##i < K) ? btag[rk##i + 1] : 0;
        C16(DECLR)
        for (int j = 0; j < 32; ++j) {
            #define STEPR(i) if (j < rs##i) { \
                const int t_ = rt##i - 1 - j; \
                rc##i = bt[t_ * NTAG + rc##i]; \
                if (lane == 0) orow[t_] = rc##i; }
            C16(STEPR)
        }
    }
}

extern "C" void kernel_launch(void* const* d_in, const int* in_sizes, int n_in,
                              void* d_out, int out_size, void* d_ws, size_t ws_size,
                              hipStream_t stream) {
    const float* emissions = (const float*)d_in[0];
    const float* mask      = (const float*)d_in[1];
    const float* trans     = (const float*)d_in[2];
    int* out = (int*)d_out;

    (void)hipFuncSetAttribute((const void*)crf_viterbi,
                              hipFuncAttributeMaxDynamicSharedMemorySize,
                              LDS_BYTES);

    crf_viterbi<<<NBATCH, 256, LDS_BYTES, stream>>>(emissions, mask, trans, out);
}

// Round 23
// 900.666 us; speedup vs baseline: 4.8289x; 1.2621x over previous
//
#include <hip/hip_runtime.h>

#define NBATCH 256
#define SLEN   2048
#define NTAG   64
#define BOS_T  1
#define EOS_T  2

#define BT_BYTES  131072
#define RING_ROWS 32
#define RING_BYTES (RING_ROWS * NTAG * 4)          // 8192
#define FLAG_OFF  (BT_BYTES + RING_BYTES)          // 139264
#define PRG_OFF   (FLAG_OFF + 16)                  // 139280
#define MAPS_OFF  (PRG_OFF + 16)                   // 139296 (64x64 u8)
#define BTAG_OFF  (MAPS_OFF + 4096)                // 143392 (65 x i32)
#define LDS_BYTES (BTAG_OFF + 272)                 // 143664 < 160K

#define GRING_FLOATS (RING_ROWS * NTAG)            // per batch
#define GRING_BYTES  ((size_t)NBATCH * GRING_FLOATS * 4)   // 2 MB

typedef float f32x2 __attribute__((ext_vector_type(2)));
typedef float f32x4 __attribute__((ext_vector_type(4)));

#define Q16(X) X(0) X(1) X(2) X(3) X(4) X(5) X(6) X(7) \
               X(8) X(9) X(10) X(11) X(12) X(13) X(14) X(15)

// T column as 32 f32x2 pairs
#define DECL_TP(q) \
  f32x2 tpA##q = { trans[(4*(q)+0)*NTAG + lane], trans[(4*(q)+1)*NTAG + lane] }; \
  f32x2 tpB##q = { trans[(4*(q)+2)*NTAG + lane], trans[(4*(q)+3)*NTAG + lane] };
#define KEEP_TP(q) asm volatile("" : "+v"(tpA##q), "+v"(tpB##q));

// producer: loop-carried row registers (read back right after the write)
#define DECL_RRV(q) f32x4 rr##q;
#define LOAD_RR(q)  rr##q = rp[q];

// producer packed candidates: v_pk_add_f32 + quad max (exact)
#define PKC(q) \
  f32x2 cpA##q = (f32x2){rr##q[0], rr##q[1]} + tpA##q; \
  f32x2 cpB##q = (f32x2){rr##q[2], rr##q[3]} + tpB##q; \
  float qm##q = fmaxf(fmaxf(fmaxf(cpA##q[0], cpA##q[1]), cpB##q[0]), cpB##q[1]);

#define FM3(x, y, z) fmaxf(fmaxf((x), (y)), (z))

// consumer: row quads from LDS ring or from L2 global ring (VECTOR loads)
#define DECL_RR(q) f32x4 cr##q = rp[q];
#define MKCD(q, a0, a1, a2, a3) \
  float cd##a0 = cr##q[0] + tpA##q[0]; float cd##a1 = cr##q[1] + tpA##q[1]; \
  float cd##a2 = cr##q[2] + tpB##q[0]; float cd##a3 = cr##q[3] + tpB##q[1];
#define ALL_CD() \
  MKCD(0,0,1,2,3)      MKCD(1,4,5,6,7)      MKCD(2,8,9,10,11)    MKCD(3,12,13,14,15) \
  MKCD(4,16,17,18,19)  MKCD(5,20,21,22,23)  MKCD(6,24,25,26,27)  MKCD(7,28,29,30,31) \
  MKCD(8,32,33,34,35)  MKCD(9,36,37,38,39)  MKCD(10,40,41,42,43) MKCD(11,44,45,46,47) \
  MKCD(12,48,49,50,51) MKCD(13,52,53,54,55) MKCD(14,56,57,58,59) MKCD(15,60,61,62,63)

// exact first-occurrence argmax tournament (ascending pairs, >= left-bias)
#define LEAF(i, pa, pb) \
  float va##i; int ia##i; { bool g_ = (cd##pa >= cd##pb); \
    va##i = g_ ? cd##pa : cd##pb; ia##i = g_ ? (pa) : (pb); }
#define MRG(vo, io, vA, iA, vB, iB) \
  float vo; int io; { bool g_ = ((vA) >= (vB)); \
    vo = g_ ? (vA) : (vB); io = g_ ? (iA) : (iB); }

__global__ __launch_bounds__(256)
__attribute__((amdgpu_waves_per_eu(1, 1)))
void crf_viterbi(const float* __restrict__ emissions,  // [B,S,C]
                 const float* __restrict__ mask,       // [B,S]
                 const float* __restrict__ trans,      // [C,C]
                 int* __restrict__ out,                // [B,S] int32 tags
                 float* __restrict__ gring)            // [B][32][64] or null
{
    extern __shared__ unsigned char lds[];
    unsigned char* bt   = lds;                               // [S-1][64]
    float*         ring = (float*)(lds + BT_BYTES);          // [32][64]
    volatile unsigned* flg = (volatile unsigned*)(lds + FLAG_OFF);
    volatile unsigned* prg = (volatile unsigned*)(lds + PRG_OFF);
    unsigned char* maps = lds + MAPS_OFF;                    // [64][64]
    int*           btag = (int*)(lds + BTAG_OFF);            // [65]

    const int b    = blockIdx.x;
    const int tid  = threadIdx.x;
    const int w    = tid >> 6;                               // wave 0..3
    const int lane = tid & 63;
    const bool useg = (gring != nullptr);                    // uniform
    float* gbase = useg ? (gring + (size_t)b * GRING_FLOATS) : nullptr;

    if (tid == 0) flg[0] = 0u;
    if (tid >= 1 && tid <= 3) prg[tid] = 0u;
    __syncthreads();

    // length = sum(mask[b,:])
    const float* mrow = mask + (size_t)b * SLEN;
    float msum = 0.f;
    #pragma unroll
    for (int k = 0; k < SLEN / 64; ++k) msum += mrow[lane + k * 64];
    #pragma unroll
    for (int off = 32; off >= 1; off >>= 1) msum += __shfl_xor(msum, off, 64);
    const int len = (int)msum;                               // in [1024, 2048]
    const int K   = (len - 1 + 31) >> 5;                     // backtrace chunks

    const float* E = emissions + (size_t)b * SLEN * NTAG;
    int* orow = out + (size_t)b * SLEN;

    if (w == 0) {
        // ---- producer: value-only; LDS readback for self; 1 coalesced global
        // store/iter mirrors the row to L2 so consumers stay OFF the LDS pipe ----
        Q16(DECL_TP)
        Q16(DECL_RRV)

        float a = E[lane] + tpA0[1];                         // alpha0 (+T[BOS])
        ring[lane] = a;                                      // row 0 -> slot 0
        if (useg) gbase[lane] = a;                           // global row 0
        {
            const f32x4* rp = (const f32x4*)ring;
            Q16(LOAD_RR)                                     // read back row 0
        }
        asm volatile("" ::: "memory");
        if (lane == 0) flg[0] = 1u;

        float e0 = E[NTAG + lane];
        float e1 = E[((2 < len) ? 2 : (len - 1)) * NTAG + lane];
        float e2 = E[((3 < len) ? 3 : (len - 1)) * NTAG + lane];
        float e3 = E[((4 < len) ? 4 : (len - 1)) * NTAG + lane];

        for (int t = 1; t < len; ++t) {
            float emit = e0; e0 = e1; e1 = e2; e2 = e3;
            int tn = (t + 4 < len) ? (t + 4) : (len - 1);
            e3 = E[tn * NTAG + lane];

            // compute from rr (= row t-1, already in registers)
            Q16(PKC)
            float s0 = FM3(qm0,  qm1,  qm2);
            float s1 = FM3(qm3,  qm4,  qm5);
            float s2 = FM3(qm6,  qm7,  qm8);
            float s3 = FM3(qm9,  qm10, qm11);
            float s4 = FM3(qm12, qm13, qm14);
            float u0 = FM3(s0, s1, s2);
            float u1 = fmaxf(s3, s4);
            float mx = FM3(u0, u1, qm15);

            a = mx + emit;
            const int slot = t & (RING_ROWS - 1);
            ring[(slot << 6) + lane] = a;                    // LDS row t
            {
                const f32x4* rp = (const f32x4*)(ring + (slot << 6));
                Q16(LOAD_RR)                                 // read back row t
            }
            if (useg) {
                gbase[(slot << 6) + lane] = a;               // L2 row t (coalesced)
                // 2 vmem/iter; vmcnt(14) => stores >=7 iters old retired:
                // when flag = t+1, global rows <= t-7 are visible
                asm volatile("s_waitcnt vmcnt(14)" ::: "memory");
            }
            asm volatile("" ::: "memory");
            if (lane == 0) flg[0] = (unsigned)(t + 1);

            // ring-overwrite guard (32-row ring, threshold t-16)
            if ((t & 7) == 0) {
                int g = 0;
                for (;;) {
                    unsigned m1_ = prg[1], m2_ = prg[2], m3_ = prg[3];
                    unsigned mn = m1_ < m2_ ? m1_ : m2_;
                    mn = mn < m3_ ? mn : m3_;
                    if ((int)mn >= t - 16 || ++g > 2000000) break;
                    __builtin_amdgcn_s_sleep(8);
                }
            }
            Q16(KEEP_TP)                                     // pin T column
        }

        // drain stores, then sentinel flag unblocks tail consumers
        if (useg) asm volatile("s_waitcnt vmcnt(0)" ::: "memory");
        asm volatile("" ::: "memory");
        if (lane == 0) flg[0] = (unsigned)(len + 64);

        // final scores + argmax (value desc, index asc)
        float fin = a + trans[lane * NTAG + EOS_T];
        float v = fin; int idx = lane;
        #pragma unroll
        for (int off = 1; off < 64; off <<= 1) {
            float ov = __shfl_xor(v, off, 64);
            int   oi = __shfl_xor(idx, off, 64);
            if (ov > v || (ov == v && oi < idx)) { v = ov; idx = oi; }
        }
        int best_last = idx;

        for (int i = len + lane; i < SLEN; i += 64) orow[i] = 0;   // PAD
        if (lane == 0) {
            orow[len - 1] = best_last;
            btag[K] = best_last;                             // backtrace seed
        }
    } else {
        // ---- consumers: lagged exact argmax -> bt; rows via L2 VECTOR loads
        // when gring present (zero LDS-pipe contention), else LDS (r19) ----
        Q16(DECL_TP)
        for (int t = w; t < len; t += 3) {
            const unsigned need = useg ? (unsigned)(t + 7) : (unsigned)t;
            int g = 0;
            while (flg[0] < need) {                          // row t-1 certified
                __builtin_amdgcn_s_sleep(16);
                if (++g > 200000) break;
            }
            asm volatile("" ::: "memory");                   // pin loads after poll

            const int slot = (t - 1) & (RING_ROWS - 1);
            const f32x4* rp = useg
                ? (const f32x4*)(gbase + (slot << 6))
                : (const f32x4*)(ring + (slot << 6));
            Q16(DECL_RR)
            ALL_CD()

            LEAF(0,  0,  1)  LEAF(1,  2,  3)  LEAF(2,  4,  5)  LEAF(3,  6,  7)
            LEAF(4,  8,  9)  LEAF(5,  10, 11) LEAF(6,  12, 13) LEAF(7,  14, 15)
            LEAF(8,  16, 17) LEAF(9,  18, 19) LEAF(10, 20, 21) LEAF(11, 22, 23)
            LEAF(12, 24, 25) LEAF(13, 26, 27) LEAF(14, 28, 29) LEAF(15, 30, 31)
            LEAF(16, 32, 33) LEAF(17, 34, 35) LEAF(18, 36, 37) LEAF(19, 38, 39)
            LEAF(20, 40, 41) LEAF(21, 42, 43) LEAF(22, 44, 45) LEAF(23, 46, 47)
            LEAF(24, 48, 49) LEAF(25, 50, 51) LEAF(26, 52, 53) LEAF(27, 54, 55)
            LEAF(28, 56, 57) LEAF(29, 58, 59) LEAF(30, 60, 61) LEAF(31, 62, 63)
            MRG(vb0,  ib0,  va0,  ia0,  va1,  ia1)   MRG(vb1,  ib1,  va2,  ia2,  va3,  ia3)
            MRG(vb2,  ib2,  va4,  ia4,  va5,  ia5)   MRG(vb3,  ib3,  va6,  ia6,  va7,  ia7)
            MRG(vb4,  ib4,  va8,  ia8,  va9,  ia9)   MRG(vb5,  ib5,  va10, ia10, va11, ia11)
            MRG(vb6,  ib6,  va12, ia12, va13, ia13)  MRG(vb7,  ib7,  va14, ia14, va15, ia15)
            MRG(vb8,  ib8,  va16, ia16, va17, ia17)  MRG(vb9,  ib9,  va18, ia18, va19, ia19)
            MRG(vb10, ib10, va20, ia20, va21, ia21)  MRG(vb11, ib11, va22, ia22, va23, ia23)
            MRG(vb12, ib12, va24, ia24, va25, ia25)  MRG(vb13, ib13, va26, ia26, va27, ia27)
            MRG(vb14, ib14, va28, ia28, va29, ia29)  MRG(vb15, ib15, va30, ia30, va31, ia31)
            MRG(vc0, ic0, vb0,  ib0,  vb1,  ib1)     MRG(vc1, ic1, vb2,  ib2,  vb3,  ib3)
            MRG(vc2, ic2, vb4,  ib4,  vb5,  ib5)     MRG(vc3, ic3, vb6,  ib6,  vb7,  ib7)
            MRG(vc4, ic4, vb8,  ib8,  vb9,  ib9)     MRG(vc5, ic5, vb10, ib10, vb11, ib11)
            MRG(vc6, ic6, vb12, ib12, vb13, ib13)    MRG(vc7, ic7, vb14, ib14, vb15, ib15)
            MRG(vd0, id0, vc0, ic0, vc1, ic1)        MRG(vd1, id1, vc2, ic2, vc3, ic3)
            MRG(vd2, id2, vc4, ic4, vc5, ic5)        MRG(vd3, id3, vc6, ic6, vc7, ic7)
            MRG(ve0, ie0, vd0, id0, vd1, id1)        MRG(ve1, ie1, vd2, id2, vd3, id3)
            MRG(vf0, if0, ve0, ie0, ve1, ie1)

            bt[(t - 1) * NTAG + lane] = (unsigned char)if0;
            asm volatile("" ::: "memory");
            prg[w] = (unsigned)t;
            Q16(KEEP_TP)
        }
        asm volatile("" ::: "memory");
        prg[w] = 0x7fffffffu;                                // done marker
    }

    // ==================== join: bt + seed visible to all ====================
    __syncthreads();

    // ---- phase 1: per-chunk tag maps; wave w owns chunks w, w+4, ... ----
    {
        #define C16(X) X(0) X(1) X(2) X(3) X(4) X(5) X(6) X(7) \
                       X(8) X(9) X(10) X(11) X(12) X(13) X(14) X(15)
        #define DECLCUR(i) \
          const int k##i = w + 4*(i); const int base##i = k##i << 5; \
          int top##i = base##i + 32; if (top##i > len - 1) top##i = len - 1; \
          const int steps##i = (k##i < K) ? (top##i - base##i) : 0; \
          int cur##i = lane;
        C16(DECLCUR)
        for (int j = 0; j < 32; ++j) {
            #define STEPC(i) if (j < steps##i) \
                cur##i = bt[(top##i - 1 - j) * NTAG + cur##i];
            C16(STEPC)
        }
        #define STOREM(i) if (k##i < K) maps[(k##i << 6) + lane] = (unsigned char)cur##i;
        C16(STOREM)
    }
    __syncthreads();

    // ---- phase 2: compose boundary tags (wave 0) ----
    if (w == 0) {
        int cur = btag[K];
        for (int k = K - 1; k >= 0; --k) {
            cur = maps[(k << 6) + cur];
            if (lane == 0) btag[k] = cur;
        }
    }
    __syncthreads();

    // ---- phase 3: guided re-chase, write outputs ----
    {
        #define DECLR(i) \
          const int rk##i = w + 4*(i); const int rb##i = rk##i << 5; \
          int rt##i = rb##i + 32; if (rt##i > len - 1) rt##i = len - 1; \
          const int rs##i = (rk##i < K) ? (rt##i - rb##i) : 0; \
          int rc##i = (rk##i < K) ? btag[rk##i + 1] : 0;
        C16(DECLR)
        for (int j = 0; j < 32; ++j) {
            #define STEPR(i) if (j < rs##i) { \
                const int t_ = rt##i - 1 - j; \
                rc##i = bt[t_ * NTAG + rc##i]; \
                if (lane == 0) orow[t_] = rc##i; }
            C16(STEPR)
        }
    }
}

extern "C" void kernel_launch(void* const* d_in, const int* in_sizes, int n_in,
                              void* d_out, int out_size, void* d_ws, size_t ws_size,
                              hipStream_t stream) {
    const float* emissions = (const float*)d_in[0];
    const float* mask      = (const float*)d_in[1];
    const float* trans     = (const float*)d_in[2];
    int* out = (int*)d_out;

    // use the global ring only if the workspace is big enough (2 MB)
    float* gring = (ws_size >= GRING_BYTES) ? (float*)d_ws : nullptr;

    (void)hipFuncSetAttribute((const void*)crf_viterbi,
                              hipFuncAttributeMaxDynamicSharedMemorySize,
                              LDS_BYTES);

    crf_viterbi<<<NBATCH, 256, LDS_BYTES, stream>>>(emissions, mask, trans, out, gring);
}

// Round 24
// 792.139 us; speedup vs baseline: 5.4905x; 1.1370x over previous
//
#include <hip/hip_runtime.h>

#define NBATCH 256
#define SLEN   2048
#define NTAG   64
#define BOS_T  1
#define EOS_T  2

#define BT_BYTES  131072
#define RING_ROWS 32
#define RING_BYTES (RING_ROWS * NTAG * 4)          // 8192
#define FLAG_OFF  (BT_BYTES + RING_BYTES)          // 139264
#define PRG_OFF   (FLAG_OFF + 16)                  // 139280
#define MAPS_OFF  (PRG_OFF + 16)                   // 139296 (64x64 u8)
#define BTAG_OFF  (MAPS_OFF + 4096)                // 143392 (65 x i32)
#define LDS_BYTES (BTAG_OFF + 272)                 // 143664 < 160K

typedef float f32x2 __attribute__((ext_vector_type(2)));
typedef float f32x4 __attribute__((ext_vector_type(4)));

#define Q16(X) X(0) X(1) X(2) X(3) X(4) X(5) X(6) X(7) \
               X(8) X(9) X(10) X(11) X(12) X(13) X(14) X(15)

// T column as 32 f32x2 pairs
#define DECL_TP(q) \
  f32x2 tpA##q = { trans[(4*(q)+0)*NTAG + lane], trans[(4*(q)+1)*NTAG + lane] }; \
  f32x2 tpB##q = { trans[(4*(q)+2)*NTAG + lane], trans[(4*(q)+3)*NTAG + lane] };
#define KEEP_TP(q) asm volatile("" : "+v"(tpA##q), "+v"(tpB##q));

// producer: loop-carried row registers (read back AFTER publishing the flag;
// the lgkmcnt wait lands at next iteration's first use -> latency hidden)
#define DECL_RRV(q) f32x4 rr##q;
#define LOAD_RR(q)  rr##q = rp[q];

// producer packed candidates: v_pk_add_f32 + quad max (exact)
#define PKC(q) \
  f32x2 cpA##q = (f32x2){rr##q[0], rr##q[1]} + tpA##q; \
  f32x2 cpB##q = (f32x2){rr##q[2], rr##q[3]} + tpB##q; \
  float qm##q = fmaxf(fmaxf(fmaxf(cpA##q[0], cpA##q[1]), cpB##q[0]), cpB##q[1]);

#define FM3(x, y, z) fmaxf(fmaxf((x), (y)), (z))

// consumer: scalar candidates (same values, exact)
#define DECL_RR(q) f32x4 cr##q = rp[q];
#define MKCD(q, a0, a1, a2, a3) \
  float cd##a0 = cr##q[0] + tpA##q[0]; float cd##a1 = cr##q[1] + tpA##q[1]; \
  float cd##a2 = cr##q[2] + tpB##q[0]; float cd##a3 = cr##q[3] + tpB##q[1];
#define ALL_CD() \
  MKCD(0,0,1,2,3)      MKCD(1,4,5,6,7)      MKCD(2,8,9,10,11)    MKCD(3,12,13,14,15) \
  MKCD(4,16,17,18,19)  MKCD(5,20,21,22,23)  MKCD(6,24,25,26,27)  MKCD(7,28,29,30,31) \
  MKCD(8,32,33,34,35)  MKCD(9,36,37,38,39)  MKCD(10,40,41,42,43) MKCD(11,44,45,46,47) \
  MKCD(12,48,49,50,51) MKCD(13,52,53,54,55) MKCD(14,56,57,58,59) MKCD(15,60,61,62,63)

// exact first-occurrence argmax tournament (ascending pairs, >= left-bias)
#define LEAF(i, pa, pb) \
  float va##i; int ia##i; { bool g_ = (cd##pa >= cd##pb); \
    va##i = g_ ? cd##pa : cd##pb; ia##i = g_ ? (pa) : (pb); }
#define MRG(vo, io, vA, iA, vB, iB) \
  float vo; int io; { bool g_ = ((vA) >= (vB)); \
    vo = g_ ? (vA) : (vB); io = g_ ? (iA) : (iB); }

__global__ __launch_bounds__(256)
__attribute__((amdgpu_waves_per_eu(1, 1)))
void crf_viterbi(const float* __restrict__ emissions,  // [B,S,C]
                 const float* __restrict__ mask,       // [B,S]
                 const float* __restrict__ trans,      // [C,C]
                 int* __restrict__ out)                // [B,S] int32 tags
{
    extern __shared__ unsigned char lds[];
    unsigned char* bt   = lds;                               // [S-1][64]
    float*         ring = (float*)(lds + BT_BYTES);          // [32][64]
    volatile unsigned* flg = (volatile unsigned*)(lds + FLAG_OFF);
    volatile unsigned* prg = (volatile unsigned*)(lds + PRG_OFF);
    unsigned char* maps = lds + MAPS_OFF;                    // [64][64]
    int*           btag = (int*)(lds + BTAG_OFF);            // [65]

    const int b    = blockIdx.x;
    const int tid  = threadIdx.x;
    const int w    = tid >> 6;                               // wave 0..3
    const int lane = tid & 63;

    if (tid == 0) flg[0] = 0u;
    if (tid >= 1 && tid <= 3) prg[tid] = 0u;
    __syncthreads();

    // length = sum(mask[b,:])
    const float* mrow = mask + (size_t)b * SLEN;
    float msum = 0.f;
    #pragma unroll
    for (int k = 0; k < SLEN / 64; ++k) msum += mrow[lane + k * 64];
    #pragma unroll
    for (int off = 32; off >= 1; off >>= 1) msum += __shfl_xor(msum, off, 64);
    const int len = (int)msum;                               // in [1024, 2048]
    const int K   = (len - 1 + 31) >> 5;                     // backtrace chunks

    const float* E = emissions + (size_t)b * SLEN * NTAG;
    int* orow = out + (size_t)b * SLEN;

    if (w == 0) {
        // ---- producer: value-only. Publish order: row write -> compiler
        // barrier -> flag -> read-back (unpinned, drains into next iter) ----
        Q16(DECL_TP)
        Q16(DECL_RRV)

        float a = E[lane] + tpA0[1];                         // alpha0 (+T[BOS])
        ring[lane] = a;                                      // row 0 -> slot 0
        asm volatile("" ::: "memory");
        if (lane == 0) flg[0] = 1u;
        {
            const f32x4* rp = (const f32x4*)ring;
            Q16(LOAD_RR)                                     // read back row 0
        }

        float e0 = E[NTAG + lane];
        float e1 = E[((2 < len) ? 2 : (len - 1)) * NTAG + lane];
        float e2 = E[((3 < len) ? 3 : (len - 1)) * NTAG + lane];
        float e3 = E[((4 < len) ? 4 : (len - 1)) * NTAG + lane];

        for (int t = 1; t < len; ++t) {
            float emit = e0; e0 = e1; e1 = e2; e2 = e3;
            int tn = (t + 4 < len) ? (t + 4) : (len - 1);
            e3 = E[tn * NTAG + lane];

            // compute from rr (= row t-1, already in registers)
            Q16(PKC)
            float s0 = FM3(qm0,  qm1,  qm2);
            float s1 = FM3(qm3,  qm4,  qm5);
            float s2 = FM3(qm6,  qm7,  qm8);
            float s3 = FM3(qm9,  qm10, qm11);
            float s4 = FM3(qm12, qm13, qm14);
            float u0 = FM3(s0, s1, s2);
            float u1 = fmaxf(s3, s4);
            float mx = FM3(u0, u1, qm15);

            a = mx + emit;
            const int slot = t & (RING_ROWS - 1);
            ring[(slot << 6) + lane] = a;                    // publish row t
            asm volatile("" ::: "memory");                   // row before flag
            if (lane == 0) flg[0] = (unsigned)(t + 1);       // flag EARLY
            {
                // read back row t; NO barrier after -> wait sinks to next use
                const f32x4* rp = (const f32x4*)(ring + (slot << 6));
                Q16(LOAD_RR)
            }

            // ring-overwrite guard (32-row ring, threshold t-16)
            if ((t & 7) == 0) {
                int g = 0;
                for (;;) {
                    unsigned m1_ = prg[1], m2_ = prg[2], m3_ = prg[3];
                    unsigned mn = m1_ < m2_ ? m1_ : m2_;
                    mn = mn < m3_ ? mn : m3_;
                    if ((int)mn >= t - 16 || ++g > 2000000) break;
                    __builtin_amdgcn_s_sleep(8);
                }
            }
            Q16(KEEP_TP)                                     // pin T column
        }

        // final scores + argmax (value desc, index asc)
        float fin = a + trans[lane * NTAG + EOS_T];
        float v = fin; int idx = lane;
        #pragma unroll
        for (int off = 1; off < 64; off <<= 1) {
            float ov = __shfl_xor(v, off, 64);
            int   oi = __shfl_xor(idx, off, 64);
            if (ov > v || (ov == v && oi < idx)) { v = ov; idx = oi; }
        }
        int best_last = idx;

        for (int i = len + lane; i < SLEN; i += 64) orow[i] = 0;   // PAD
        if (lane == 0) {
            orow[len - 1] = best_last;
            btag[K] = best_last;                             // backtrace seed
        }
    } else {
        // ---- consumers: lagged exact argmax -> bt (r19, poll backoff 32) ----
        Q16(DECL_TP)
        for (int t = w; t < len; t += 3) {
            int g = 0;
            while (flg[0] < (unsigned)t) {                   // rows <= t-1 ready
                __builtin_amdgcn_s_sleep(32);
                if (++g > 100000) break;
            }
            asm volatile("" ::: "memory");

            const f32x4* rp = (const f32x4*)(ring + (((t - 1) & (RING_ROWS - 1)) << 6));
            Q16(DECL_RR)
            ALL_CD()

            LEAF(0,  0,  1)  LEAF(1,  2,  3)  LEAF(2,  4,  5)  LEAF(3,  6,  7)
            LEAF(4,  8,  9)  LEAF(5,  10, 11) LEAF(6,  12, 13) LEAF(7,  14, 15)
            LEAF(8,  16, 17) LEAF(9,  18, 19) LEAF(10, 20, 21) LEAF(11, 22, 23)
            LEAF(12, 24, 25) LEAF(13, 26, 27) LEAF(14, 28, 29) LEAF(15, 30, 31)
            LEAF(16, 32, 33) LEAF(17, 34, 35) LEAF(18, 36, 37) LEAF(19, 38, 39)
            LEAF(20, 40, 41) LEAF(21, 42, 43) LEAF(22, 44, 45) LEAF(23, 46, 47)
            LEAF(24, 48, 49) LEAF(25, 50, 51) LEAF(26, 52, 53) LEAF(27, 54, 55)
            LEAF(28, 56, 57) LEAF(29, 58, 59) LEAF(30, 60, 61) LEAF(31, 62, 63)
            MRG(vb0,  ib0,  va0,  ia0,  va1,  ia1)   MRG(vb1,  ib1,  va2,  ia2,  va3,  ia3)
            MRG(vb2,  ib2,  va4,  ia4,  va5,  ia5)   MRG(vb3,  ib3,  va6,  ia6,  va7,  ia7)
            MRG(vb4,  ib4,  va8,  ia8,  va9,  ia9)   MRG(vb5,  ib5,  va10, ia10, va11, ia11)
            MRG(vb6,  ib6,  va12, ia12, va13, ia13)  MRG(vb7,  ib7,  va14, ia14, va15, ia15)
            MRG(vb8,  ib8,  va16, ia16, va17, ia17)  MRG(vb9,  ib9,  va18, ia18, va19, ia19)
            MRG(vb10, ib10, va20, ia20, va21, ia21)  MRG(vb11, ib11, va22, ia22, va23, ia23)
            MRG(vb12, ib12, va24, ia24, va25, ia25)  MRG(vb13, ib13, va26, ia26, va27, ia27)
            MRG(vb14, ib14, va28, ia28, va29, ia29)  MRG(vb15, ib15, va30, ia30, va31, ia31)
            MRG(vc0, ic0, vb0,  ib0,  vb1,  ib1)     MRG(vc1, ic1, vb2,  ib2,  vb3,  ib3)
            MRG(vc2, ic2, vb4,  ib4,  vb5,  ib5)     MRG(vc3, ic3, vb6,  ib6,  vb7,  ib7)
            MRG(vc4, ic4, vb8,  ib8,  vb9,  ib9)     MRG(vc5, ic5, vb10, ib10, vb11, ib11)
            MRG(vc6, ic6, vb12, ib12, vb13, ib13)    MRG(vc7, ic7, vb14, ib14, vb15, ib15)
            MRG(vd0, id0, vc0, ic0, vc1, ic1)        MRG(vd1, id1, vc2, ic2, vc3, ic3)
            MRG(vd2, id2, vc4, ic4, vc5, ic5)        MRG(vd3, id3, vc6, ic6, vc7, ic7)
            MRG(ve0, ie0, vd0, id0, vd1, id1)        MRG(ve1, ie1, vd2, id2, vd3, id3)
            MRG(vf0, if0, ve0, ie0, ve1, ie1)

            bt[(t - 1) * NTAG + lane] = (unsigned char)if0;
            asm volatile("" ::: "memory");
            prg[w] = (unsigned)t;
            Q16(KEEP_TP)
        }
    }

    // ==================== join: bt + seed visible to all ====================
    __syncthreads();

    // ---- phase 1: per-chunk tag maps; wave w owns chunks w, w+4, ... ----
    {
        #define C16(X) X(0) X(1) X(2) X(3) X(4) X(5) X(6) X(7) \
                       X(8) X(9) X(10) X(11) X(12) X(13) X(14) X(15)
        #define DECLCUR(i) \
          const int k##i = w + 4*(i); const int base##i = k##i << 5; \
          int top##i = base##i + 32; if (top##i > len - 1) top##i = len - 1; \
          const int steps##i = (k##i < K) ? (top##i - base##i) : 0; \
          int cur##i = lane;
        C16(DECLCUR)
        for (int j = 0; j < 32; ++j) {
            #define STEPC(i) if (j < steps##i) \
                cur##i = bt[(top##i - 1 - j) * NTAG + cur##i];
            C16(STEPC)
        }
        #define STOREM(i) if (k##i < K) maps[(k##i << 6) + lane] = (unsigned char)cur##i;
        C16(STOREM)
    }
    __syncthreads();

    // ---- phase 2: compose boundary tags (wave 0) ----
    if (w == 0) {
        int cur = btag[K];
        for (int k = K - 1; k >= 0; --k) {
            cur = maps[(k << 6) + cur];
            if (lane == 0) btag[k] = cur;
        }
    }
    __syncthreads();

    // ---- phase 3: guided re-chase, write outputs ----
    {
        #define DECLR(i) \
          const int rk##i = w + 4*(i); const int rb##i = rk##i << 5; \
          int rt##i = rb##i + 32; if (rt##i > len - 1) rt##i = len - 1; \
          const int rs##i = (rk##i < K) ? (rt##i - rb##i) : 0; \
          int rc##i = (rk##i < K) ? btag[rk##i + 1] : 0;
        C16(DECLR)
        for (int j = 0; j < 32; ++j) {
            #define STEPR(i) if (j < rs##i) { \
                const int t_ = rt##i - 1 - j; \
                rc##i = bt[t_ * NTAG + rc##i]; \
                if (lane == 0) orow[t_] = rc##i; }
            C16(STEPR)
        }
    }
}

extern "C" void kernel_launch(void* const* d_in, const int* in_sizes, int n_in,
                              void* d_out, int out_size, void* d_ws, size_t ws_size,
                              hipStream_t stream) {
    const float* emissions = (const float*)d_in[0];
    const float* mask      = (const float*)d_in[1];
    const float* trans     = (const float*)d_in[2];
    int* out = (int*)d_out;

    (void)hipFuncSetAttribute((const void*)crf_viterbi,
                              hipFuncAttributeMaxDynamicSharedMemorySize,
                              LDS_BYTES);

    crf_viterbi<<<NBATCH, 256, LDS_BYTES, stream>>>(emissions, mask, trans, out);
}

// Round 25
// 743.547 us; speedup vs baseline: 5.8493x; 1.0654x over previous
//
#include <hip/hip_runtime.h>

#define NBATCH 256
#define SLEN   2048
#define NTAG   64
#define BOS_T  1
#define EOS_T  2

#define BT_BYTES  131072
#define RING_ROWS 32
#define RING_BYTES (RING_ROWS * NTAG * 4)          // 8192
#define FLAG_OFF  (BT_BYTES + RING_BYTES)          // 139264
#define PRG_OFF   (FLAG_OFF + 16)                  // 139280
#define MAPS_OFF  (PRG_OFF + 16)                   // 139296 (64x64 u8)
#define BTAG_OFF  (MAPS_OFF + 4096)                // 143392 (65 x i32)
#define LDS_BYTES (BTAG_OFF + 272)                 // 143664 < 160K

typedef float f32x2 __attribute__((ext_vector_type(2)));
typedef float f32x4 __attribute__((ext_vector_type(4)));

#define Q16(X) X(0) X(1) X(2) X(3) X(4) X(5) X(6) X(7) \
               X(8) X(9) X(10) X(11) X(12) X(13) X(14) X(15)

// T column as 32 f32x2 pairs
#define DECL_TP(q) \
  f32x2 tpA##q = { trans[(4*(q)+0)*NTAG + lane], trans[(4*(q)+1)*NTAG + lane] }; \
  f32x2 tpB##q = { trans[(4*(q)+2)*NTAG + lane], trans[(4*(q)+3)*NTAG + lane] };
#define KEEP_TP(q) asm volatile("" : "+v"(tpA##q), "+v"(tpB##q));

// producer: loop-carried row registers (read back right after the write)
#define DECL_RRV(q) f32x4 rr##q;
#define LOAD_RR(q)  rr##q = rp[q];

// producer packed candidates: v_pk_add_f32 + quad max (exact)
#define PKC(q) \
  f32x2 cpA##q = (f32x2){rr##q[0], rr##q[1]} + tpA##q; \
  f32x2 cpB##q = (f32x2){rr##q[2], rr##q[3]} + tpB##q; \
  float qm##q = fmaxf(fmaxf(fmaxf(cpA##q[0], cpA##q[1]), cpB##q[0]), cpB##q[1]);

#define FM3(x, y, z) fmaxf(fmaxf((x), (y)), (z))

// consumer: scalar candidates (same values, exact)
#define DECL_RR(q) f32x4 cr##q = rp[q];
#define MKCD(q, a0, a1, a2, a3) \
  float cd##a0 = cr##q[0] + tpA##q[0]; float cd##a1 = cr##q[1] + tpA##q[1]; \
  float cd##a2 = cr##q[2] + tpB##q[0]; float cd##a3 = cr##q[3] + tpB##q[1];
#define ALL_CD() \
  MKCD(0,0,1,2,3)      MKCD(1,4,5,6,7)      MKCD(2,8,9,10,11)    MKCD(3,12,13,14,15) \
  MKCD(4,16,17,18,19)  MKCD(5,20,21,22,23)  MKCD(6,24,25,26,27)  MKCD(7,28,29,30,31) \
  MKCD(8,32,33,34,35)  MKCD(9,36,37,38,39)  MKCD(10,40,41,42,43) MKCD(11,44,45,46,47) \
  MKCD(12,48,49,50,51) MKCD(13,52,53,54,55) MKCD(14,56,57,58,59) MKCD(15,60,61,62,63)

// exact first-occurrence argmax tournament (ascending pairs, >= left-bias)
#define LEAF(i, pa, pb) \
  float va##i; int ia##i; { bool g_ = (cd##pa >= cd##pb); \
    va##i = g_ ? cd##pa : cd##pb; ia##i = g_ ? (pa) : (pb); }
#define MRG(vo, io, vA, iA, vB, iB) \
  float vo; int io; { bool g_ = ((vA) >= (vB)); \
    vo = g_ ? (vA) : (vB); io = g_ ? (iA) : (iB); }

__global__ __launch_bounds__(256)
__attribute__((amdgpu_waves_per_eu(1, 1)))
void crf_viterbi(const float* __restrict__ emissions,  // [B,S,C]
                 const float* __restrict__ mask,       // [B,S]
                 const float* __restrict__ trans,      // [C,C]
                 int* __restrict__ out)                // [B,S] int32 tags
{
    extern __shared__ unsigned char lds[];
    unsigned char* bt   = lds;                               // [S-1][64]
    float*         ring = (float*)(lds + BT_BYTES);          // [32][64]
    volatile unsigned* flg = (volatile unsigned*)(lds + FLAG_OFF);
    volatile unsigned* prg = (volatile unsigned*)(lds + PRG_OFF);
    unsigned char* maps = lds + MAPS_OFF;                    // [64][64]
    int*           btag = (int*)(lds + BTAG_OFF);            // [65]

    const int b    = blockIdx.x;
    const int tid  = threadIdx.x;
    const int w    = tid >> 6;                               // wave 0..3
    const int lane = tid & 63;

    if (tid == 0) flg[0] = 0u;
    if (tid >= 1 && tid <= 3) prg[tid] = 0u;
    __syncthreads();

    // length = sum(mask[b,:])
    const float* mrow = mask + (size_t)b * SLEN;
    float msum = 0.f;
    #pragma unroll
    for (int k = 0; k < SLEN / 64; ++k) msum += mrow[lane + k * 64];
    #pragma unroll
    for (int off = 32; off >= 1; off >>= 1) msum += __shfl_xor(msum, off, 64);
    const int len = (int)msum;                               // in [1024, 2048]
    const int K   = (len - 1 + 31) >> 5;                     // backtrace chunks

    const float* E = emissions + (size_t)b * SLEN * NTAG;
    int* orow = out + (size_t)b * SLEN;

    if (w == 0) {
        // ---- producer: value-only; row read-back issued right after the
        // write so its latency hides under boundary bookkeeping ----
        Q16(DECL_TP)
        Q16(DECL_RRV)

        float a = E[lane] + tpA0[1];                         // alpha0 (+T[BOS])
        ring[lane] = a;                                      // row 0 -> slot 0
        {
            const f32x4* rp = (const f32x4*)ring;
            Q16(LOAD_RR)                                     // read back row 0
        }
        asm volatile("" ::: "memory");
        if (lane == 0) flg[0] = 1u;

        float e0 = E[NTAG + lane];
        float e1 = E[((2 < len) ? 2 : (len - 1)) * NTAG + lane];
        float e2 = E[((3 < len) ? 3 : (len - 1)) * NTAG + lane];
        float e3 = E[((4 < len) ? 4 : (len - 1)) * NTAG + lane];

        for (int t = 1; t < len; ++t) {
            float emit = e0; e0 = e1; e1 = e2; e2 = e3;
            int tn = (t + 4 < len) ? (t + 4) : (len - 1);
            e3 = E[tn * NTAG + lane];

            // compute from rr (= row t-1, already in registers)
            Q16(PKC)
            float s0 = FM3(qm0,  qm1,  qm2);
            float s1 = FM3(qm3,  qm4,  qm5);
            float s2 = FM3(qm6,  qm7,  qm8);
            float s3 = FM3(qm9,  qm10, qm11);
            float s4 = FM3(qm12, qm13, qm14);
            float u0 = FM3(s0, s1, s2);
            float u1 = fmaxf(s3, s4);
            float mx = FM3(u0, u1, qm15);

            a = mx + emit;
            const int slot = t & (RING_ROWS - 1);
            ring[(slot << 6) + lane] = a;                    // publish row t
            {
                // read back row t NOW; latency overlaps flag/guard/prefetch
                const f32x4* rp = (const f32x4*)(ring + (slot << 6));
                Q16(LOAD_RR)
            }
            asm volatile("" ::: "memory");
            if (lane == 0) flg[0] = (unsigned)(t + 1);

            // ring-overwrite guard (32-row ring, threshold t-16)
            if ((t & 7) == 0) {
                int g = 0;
                for (;;) {
                    unsigned m1_ = prg[1], m2_ = prg[2], m3_ = prg[3];
                    unsigned mn = m1_ < m2_ ? m1_ : m2_;
                    mn = mn < m3_ ? mn : m3_;
                    if ((int)mn >= t - 16 || ++g > 2000000) break;
                    __builtin_amdgcn_s_sleep(8);
                }
            }
            Q16(KEEP_TP)                                     // pin T column
        }

        // final scores + argmax (value desc, index asc)
        float fin = a + trans[lane * NTAG + EOS_T];
        float v = fin; int idx = lane;
        #pragma unroll
        for (int off = 1; off < 64; off <<= 1) {
            float ov = __shfl_xor(v, off, 64);
            int   oi = __shfl_xor(idx, off, 64);
            if (ov > v || (ov == v && oi < idx)) { v = ov; idx = oi; }
        }
        int best_last = idx;

        for (int i = len + lane; i < SLEN; i += 64) orow[i] = 0;   // PAD
        if (lane == 0) {
            orow[len - 1] = best_last;
            btag[K] = best_last;                             // backtrace seed
        }
    } else {
        // ---- consumers: lagged exact argmax -> bt ----
        Q16(DECL_TP)
        for (int t = w; t < len; t += 3) {
            int g = 0;
            while (flg[0] < (unsigned)t) {                   // rows <= t-1 ready
                __builtin_amdgcn_s_sleep(16);
                if (++g > 200000) break;
            }
            asm volatile("" ::: "memory");

            const f32x4* rp = (const f32x4*)(ring + (((t - 1) & (RING_ROWS - 1)) << 6));
            Q16(DECL_RR)
            ALL_CD()

            LEAF(0,  0,  1)  LEAF(1,  2,  3)  LEAF(2,  4,  5)  LEAF(3,  6,  7)
            LEAF(4,  8,  9)  LEAF(5,  10, 11) LEAF(6,  12, 13) LEAF(7,  14, 15)
            LEAF(8,  16, 17) LEAF(9,  18, 19) LEAF(10, 20, 21) LEAF(11, 22, 23)
            LEAF(12, 24, 25) LEAF(13, 26, 27) LEAF(14, 28, 29) LEAF(15, 30, 31)
            LEAF(16, 32, 33) LEAF(17, 34, 35) LEAF(18, 36, 37) LEAF(19, 38, 39)
            LEAF(20, 40, 41) LEAF(21, 42, 43) LEAF(22, 44, 45) LEAF(23, 46, 47)
            LEAF(24, 48, 49) LEAF(25, 50, 51) LEAF(26, 52, 53) LEAF(27, 54, 55)
            LEAF(28, 56, 57) LEAF(29, 58, 59) LEAF(30, 60, 61) LEAF(31, 62, 63)
            MRG(vb0,  ib0,  va0,  ia0,  va1,  ia1)   MRG(vb1,  ib1,  va2,  ia2,  va3,  ia3)
            MRG(vb2,  ib2,  va4,  ia4,  va5,  ia5)   MRG(vb3,  ib3,  va6,  ia6,  va7,  ia7)
            MRG(vb4,  ib4,  va8,  ia8,  va9,  ia9)   MRG(vb5,  ib5,  va10, ia10, va11, ia11)
            MRG(vb6,  ib6,  va12, ia12, va13, ia13)  MRG(vb7,  ib7,  va14, ia14, va15, ia15)
            MRG(vb8,  ib8,  va16, ia16, va17, ia17)  MRG(vb9,  ib9,  va18, ia18, va19, ia19)
            MRG(vb10, ib10, va20, ia20, va21, ia21)  MRG(vb11, ib11, va22, ia22, va23, ia23)
            MRG(vb12, ib12, va24, ia24, va25, ia25)  MRG(vb13, ib13, va26, ia26, va27, ia27)
            MRG(vb14, ib14, va28, ia28, va29, ia29)  MRG(vb15, ib15, va30, ia30, va31, ia31)
            MRG(vc0, ic0, vb0,  ib0,  vb1,  ib1)     MRG(vc1, ic1, vb2,  ib2,  vb3,  ib3)
            MRG(vc2, ic2, vb4,  ib4,  vb5,  ib5)     MRG(vc3, ic3, vb6,  ib6,  vb7,  ib7)
            MRG(vc4, ic4, vb8,  ib8,  vb9,  ib9)     MRG(vc5, ic5, vb10, ib10, vb11, ib11)
            MRG(vc6, ic6, vb12, ib12, vb13, ib13)    MRG(vc7, ic7, vb14, ib14, vb15, ib15)
            MRG(vd0, id0, vc0, ic0, vc1, ic1)        MRG(vd1, id1, vc2, ic2, vc3, ic3)
            MRG(vd2, id2, vc4, ic4, vc5, ic5)        MRG(vd3, id3, vc6, ic6, vc7, ic7)
            MRG(ve0, ie0, vd0, id0, vd1, id1)        MRG(ve1, ie1, vd2, id2, vd3, id3)
            MRG(vf0, if0, ve0, ie0, ve1, ie1)

            bt[(t - 1) * NTAG + lane] = (unsigned char)if0;
            asm volatile("" ::: "memory");
            prg[w] = (unsigned)t;
            Q16(KEEP_TP)
        }
    }

    // ==================== join: bt + seed visible to all ====================
    __syncthreads();

    // ---- phase 1: per-chunk tag maps; wave w owns chunks w, w+4, ... ----
    {
        #define C16(X) X(0) X(1) X(2) X(3) X(4) X(5) X(6) X(7) \
                       X(8) X(9) X(10) X(11) X(12) X(13) X(14) X(15)
        #define DECLCUR(i) \
          const int k##i = w + 4*(i); const int base##i = k##i << 5; \
          int top##i = base##i + 32; if (top##i > len - 1) top##i = len - 1; \
          const int steps##i = (k##i < K) ? (top##i - base##i) : 0; \
          int cur##i = lane;
        C16(DECLCUR)
        for (int j = 0; j < 32; ++j) {
            #define STEPC(i) if (j < steps##i) \
                cur##i = bt[(top##i - 1 - j) * NTAG + cur##i];
            C16(STEPC)
        }
        #define STOREM(i) if (k##i < K) maps[(k##i << 6) + lane] = (unsigned char)cur##i;
        C16(STOREM)
    }
    __syncthreads();

    // ---- phase 2: compose boundary tags (wave 0) ----
    if (w == 0) {
        int cur = btag[K];
        for (int k = K - 1; k >= 0; --k) {
            cur = maps[(k << 6) + cur];
            if (lane == 0) btag[k] = cur;
        }
    }
    __syncthreads();

    // ---- phase 3: guided re-chase, write outputs ----
    {
        #define DECLR(i) \
          const int rk##i = w + 4*(i); const int rb##i = rk##i << 5; \
          int rt##i = rb##i + 32; if (rt##i > len - 1) rt##i = len - 1; \
          const int rs##i = (rk##i < K) ? (rt##i - rb##i) : 0; \
          int rc##i = (rk##i < K) ? btag[rk##i + 1] : 0;
        C16(DECLR)
        for (int j = 0; j < 32; ++j) {
            #define STEPR(i) if (j < rs##i) { \
                const int t_ = rt##i - 1 - j; \
                rc##i = bt[t_ * NTAG + rc##i]; \
                if (lane == 0) orow[t_] = rc##i; }
            C16(STEPR)
        }
    }
}

extern "C" void kernel_launch(void* const* d_in, const int* in_sizes, int n_in,
                              void* d_out, int out_size, void* d_ws, size_t ws_size,
                              hipStream_t stream) {
    const float* emissions = (const float*)d_in[0];
    const float* mask      = (const float*)d_in[1];
    const float* trans     = (const float*)d_in[2];
    int* out = (int*)d_out;

    (void)hipFuncSetAttribute((const void*)crf_viterbi,
                              hipFuncAttributeMaxDynamicSharedMemorySize,
                              LDS_BYTES);

    crf_viterbi<<<NBATCH, 256, LDS_BYTES, stream>>>(emissions, mask, trans, out);
}